// Round 1
// baseline (174.768 us; speedup 1.0000x reference)
//
#include <hip/hip_runtime.h>
#include <hip/hip_bf16.h>

#define B_  16384
#define I_  512
#define H1_ 256
#define H2_ 128
#define E_  8
#define T_  2

typedef __attribute__((ext_vector_type(8))) short short8;
typedef __attribute__((ext_vector_type(4))) float float4_t;

__device__ inline unsigned short f2bf(float f) {
    union { float f; unsigned u; } v; v.f = f;
    unsigned r = v.u + 0x7FFFu + ((v.u >> 16) & 1u);
    return (unsigned short)(r >> 16);
}
__device__ inline float bf2f(unsigned short u) {
    union { unsigned u; float f; } v; v.u = ((unsigned)u) << 16;
    return v.f;
}

// async global->LDS, 16B per lane. LDS dest = wave-uniform base + lane*16.
__device__ inline void async_copy16(const unsigned short* g, unsigned short* l) {
    __builtin_amdgcn_global_load_lds(
        (const __attribute__((address_space(1))) void*)g,
        (__attribute__((address_space(3))) void*)l,
        16, 0, 0);
}

// ---------------- prep: x fp32 -> bf16 ----------------
__global__ void conv_x_kernel(const float* __restrict__ x, unsigned short* __restrict__ xb) {
    int idx = blockIdx.x * 256 + threadIdx.x;   // one thread per 8 elements
    size_t base = (size_t)idx * 8;
    float4_t a = *(const float4_t*)(x + base);
    float4_t b = *(const float4_t*)(x + base + 4);
    short8 s;
    s[0] = (short)f2bf(a[0]); s[1] = (short)f2bf(a[1]);
    s[2] = (short)f2bf(a[2]); s[3] = (short)f2bf(a[3]);
    s[4] = (short)f2bf(b[0]); s[5] = (short)f2bf(b[1]);
    s[6] = (short)f2bf(b[2]); s[7] = (short)f2bf(b[3]);
    *(short8*)(xb + base) = s;
}

// ---------------- prep: transpose [E][R][C] fp32 -> [E][C][R] bf16 ----------------
__global__ void transpose_bf16_kernel(const float* __restrict__ in, unsigned short* __restrict__ out,
                                      int R, int C) {
    __shared__ float tile[32][33];
    int e = blockIdx.z;
    int c0 = blockIdx.x * 32;
    int r0 = blockIdx.y * 32;
    const float* inp = in + (size_t)e * R * C;
    unsigned short* outp = out + (size_t)e * R * C;
    int tx = threadIdx.x, ty = threadIdx.y;   // (32, 8)
#pragma unroll
    for (int j = 0; j < 32; j += 8)
        tile[ty + j][tx] = inp[(size_t)(r0 + ty + j) * C + c0 + tx];
    __syncthreads();
#pragma unroll
    for (int j = 0; j < 32; j += 8)
        outp[(size_t)(c0 + ty + j) * R + r0 + tx] = f2bf(tile[tx][ty + j]);
}

// ---------------- prep: Wg [T][I][E] fp32 -> WgT [T*E][I] bf16 ----------------
__global__ void prep_wgt_kernel(const float* __restrict__ wg, unsigned short* __restrict__ wgt) {
    int idx = blockIdx.x * 256 + threadIdx.x;  // 16*512 = 8192
    int te = idx >> 9;
    int i  = idx & 511;
    int t = te >> 3, e = te & 7;
    wgt[(size_t)te * I_ + i] = f2bf(wg[(size_t)t * I_ * E_ + (size_t)i * E_ + e]);
}

// ---------------- gates: [B,512]x[512,16] MFMA GEMM + softmax over e ----------------
// gates layout out: [B][T][E] fp32 (16 floats per row)
__global__ void gates_kernel(const unsigned short* __restrict__ xb,
                             const unsigned short* __restrict__ wgt,
                             const float* __restrict__ bg,
                             float* __restrict__ gates) {
    int w = threadIdx.x >> 6, lane = threadIdx.x & 63;
    int row0 = (blockIdx.x * 4 + w) * 16;
    int col = lane & 15, quad = lane >> 4;
    float4_t acc = {0.f, 0.f, 0.f, 0.f};
    const unsigned short* aG = xb + (size_t)(row0 + col) * I_ + quad * 8;
    const unsigned short* bG = wgt + (size_t)col * I_ + quad * 8;
#pragma unroll
    for (int k = 0; k < I_; k += 32) {
        short8 a = *(const short8*)(aG + k);
        short8 b = *(const short8*)(bG + k);
        acc = __builtin_amdgcn_mfma_f32_16x16x32_bf16(a, b, acc, 0, 0, 0);
    }
    float bias = bg[col];   // bg is [T][E] flat == [te]
#pragma unroll
    for (int p = 0; p < 4; ++p) {
        float v = acc[p] + bias;
        float m = v;
        m = fmaxf(m, __shfl_xor(m, 1));
        m = fmaxf(m, __shfl_xor(m, 2));
        m = fmaxf(m, __shfl_xor(m, 4));
        float ev = __expf(v - m);
        float s = ev;
        s += __shfl_xor(s, 1);
        s += __shfl_xor(s, 2);
        s += __shfl_xor(s, 4);
        gates[(size_t)(row0 + quad * 4 + p) * 16 + col] = ev / s;
    }
}

// ---------------- grouped GEMM: C[e] = relu(A[e] * B[e]^T + bias[e]) in bf16 ----------------
// A: [M][K] bf16 (row-major, per-expert stride aSE; 0 => shared)
// Bt: [N][K] bf16 per expert
// C: [M][N] bf16 per expert
// 128x128 tile, BK=64, 4 waves of 64x64, 16x16x32 MFMA, XOR-swizzled LDS.
__global__ void gemm_relu_kernel(const unsigned short* __restrict__ A, size_t aSE,
                                 const unsigned short* __restrict__ Bt, size_t bSE,
                                 const float* __restrict__ bias, int biasSE,
                                 unsigned short* __restrict__ C, size_t cSE,
                                 int K, int lda, int ldb, int ldc) {
    __shared__ unsigned short As[128 * 64];
    __shared__ unsigned short Bs[128 * 64];
    int e = blockIdx.z;
    const unsigned short* Ae = A + (size_t)e * aSE;
    const unsigned short* Be = Bt + (size_t)e * bSE;
    const float* biasE = bias + (size_t)e * biasSE;
    unsigned short* Ce = C + (size_t)e * cSE;
    int m0 = blockIdx.x * 128, n0 = blockIdx.y * 128;
    int t = threadIdx.x, w = t >> 6, lane = t & 63;
    int col = lane & 15, quad = lane >> 4;
    int wm = (w & 1) * 64, wn = (w >> 1) * 64;

    float4_t acc[4][4];
#pragma unroll
    for (int mi = 0; mi < 4; ++mi)
#pragma unroll
        for (int ni = 0; ni < 4; ++ni)
            acc[mi][ni] = (float4_t){0.f, 0.f, 0.f, 0.f};

    // staging: chunk id = j*256 + t; row = cid>>3 (=j*32 + t>>3), slot = cid&7.
    // swizzle: LDS[row][slot] holds global k-chunk (slot ^ (row&7)).
    int rT = t >> 3;
    int gk = (((t & 7) ^ (rT & 7))) * 8;
    const unsigned short* aG = Ae + (size_t)(m0 + rT) * lda + gk;
    const unsigned short* bG = Be + (size_t)(n0 + rT) * ldb + gk;
    unsigned short* aL = As + (size_t)w * 64 * 8;   // + j*2048 per j
    unsigned short* bL = Bs + (size_t)w * 64 * 8;

    for (int k0 = 0; k0 < K; k0 += 64) {
#pragma unroll
        for (int j = 0; j < 4; ++j) {
            async_copy16(aG + (size_t)j * 32 * lda + k0, aL + j * 2048);
            async_copy16(bG + (size_t)j * 32 * ldb + k0, bL + j * 2048);
        }
        __syncthreads();
#pragma unroll
        for (int kk = 0; kk < 64; kk += 32) {
            int q = (kk >> 3) + quad;
            short8 af[4], bf[4];
#pragma unroll
            for (int mi = 0; mi < 4; ++mi) {
                int r = wm + mi * 16 + col;
                af[mi] = *(const short8*)&As[r * 64 + ((q ^ (r & 7)) * 8)];
            }
#pragma unroll
            for (int ni = 0; ni < 4; ++ni) {
                int r = wn + ni * 16 + col;
                bf[ni] = *(const short8*)&Bs[r * 64 + ((q ^ (r & 7)) * 8)];
            }
#pragma unroll
            for (int mi = 0; mi < 4; ++mi)
#pragma unroll
                for (int ni = 0; ni < 4; ++ni)
                    acc[mi][ni] = __builtin_amdgcn_mfma_f32_16x16x32_bf16(af[mi], bf[ni], acc[mi][ni], 0, 0, 0);
        }
        __syncthreads();
    }

#pragma unroll
    for (int ni = 0; ni < 4; ++ni) {
        int c = n0 + wn + ni * 16 + col;
        float bv = biasE[c];
#pragma unroll
        for (int mi = 0; mi < 4; ++mi) {
            int rbase = m0 + wm + mi * 16 + quad * 4;
#pragma unroll
            for (int p = 0; p < 4; ++p) {
                float v = acc[mi][ni][p] + bv;
                v = v > 0.f ? v : 0.f;
                Ce[(size_t)(rbase + p) * ldc + c] = f2bf(v);
            }
        }
    }
}

// ---------------- combine: towers[t][b][:] = sum_e gates[b][t][e] * eo[e][b][:] ----------------
__global__ void combine_kernel(const unsigned short* __restrict__ eo,
                               const float* __restrict__ gates,
                               float* __restrict__ out) {
    int idx = blockIdx.x * 256 + threadIdx.x;   // B*16 threads
    int b = idx >> 4;
    int c0 = (idx & 15) * 8;
    float ga[16];
#pragma unroll
    for (int j = 0; j < 16; ++j) ga[j] = gates[(size_t)b * 16 + j];
    float a0[8], a1[8];
#pragma unroll
    for (int j = 0; j < 8; ++j) { a0[j] = 0.f; a1[j] = 0.f; }
#pragma unroll
    for (int e = 0; e < 8; ++e) {
        short8 v = *(const short8*)(eo + ((size_t)e * B_ + b) * H2_ + c0);
        float w0 = ga[e], w1 = ga[8 + e];
#pragma unroll
        for (int j = 0; j < 8; ++j) {
            float f = bf2f((unsigned short)v[j]);
            a0[j] += w0 * f;
            a1[j] += w1 * f;
        }
    }
    float* o0 = out + (size_t)b * H2_ + c0;
    float* o1 = out + (size_t)B_ * H2_ + (size_t)b * H2_ + c0;
    *(float4_t*)o0 = (float4_t){a0[0], a0[1], a0[2], a0[3]};
    *(float4_t*)(o0 + 4) = (float4_t){a0[4], a0[5], a0[6], a0[7]};
    *(float4_t*)o1 = (float4_t){a1[0], a1[1], a1[2], a1[3]};
    *(float4_t*)(o1 + 4) = (float4_t){a1[4], a1[5], a1[6], a1[7]};
}

extern "C" void kernel_launch(void* const* d_in, const int* in_sizes, int n_in,
                              void* d_out, int out_size, void* d_ws, size_t ws_size,
                              hipStream_t stream) {
    const float* x  = (const float*)d_in[0];
    const float* W1 = (const float*)d_in[1];
    const float* b1 = (const float*)d_in[2];
    const float* W2 = (const float*)d_in[3];
    const float* b2 = (const float*)d_in[4];
    const float* Wg = (const float*)d_in[5];
    const float* bg = (const float*)d_in[6];
    float* out = (float*)d_out;

    char* ws = (char*)d_ws;
    unsigned short* xb    = (unsigned short*)(ws);                // 16,777,216 B
    unsigned short* w1t   = (unsigned short*)(ws + 16777216);     //  2,097,152 B
    unsigned short* w2t   = (unsigned short*)(ws + 18874368);     //    524,288 B
    unsigned short* wgt   = (unsigned short*)(ws + 19398656);     //     16,384 B
    float*          gates = (float*)(ws + 19415040);              //  1,048,576 B
    unsigned short* h     = (unsigned short*)(ws + 20463616);     // 67,108,864 B
    unsigned short* eo    = (unsigned short*)(ws + 87572480);     // 33,554,432 B
    // total: 121,126,912 B

    // prep
    conv_x_kernel<<<dim3(B_ * I_ / 8 / 256), 256, 0, stream>>>(x, xb);
    transpose_bf16_kernel<<<dim3(H1_ / 32, I_ / 32, E_), dim3(32, 8), 0, stream>>>(W1, w1t, I_, H1_);
    transpose_bf16_kernel<<<dim3(H2_ / 32, H1_ / 32, E_), dim3(32, 8), 0, stream>>>(W2, w2t, H1_, H2_);
    prep_wgt_kernel<<<dim3(T_ * E_ * I_ / 256), 256, 0, stream>>>(Wg, wgt);

    // gates
    gates_kernel<<<dim3(B_ / 64), 256, 0, stream>>>(xb, wgt, bg, gates);

    // layer 1: h[e] = relu(xb * w1t[e]^T + b1[e])   M=B, N=H1, K=I
    gemm_relu_kernel<<<dim3(B_ / 128, H1_ / 128, E_), 256, 0, stream>>>(
        xb, 0, w1t, (size_t)H1_ * I_, b1, H1_, h, (size_t)B_ * H1_, I_, I_, I_, H1_);

    // layer 2: eo[e] = relu(h[e] * w2t[e]^T + b2[e])   M=B, N=H2, K=H1
    gemm_relu_kernel<<<dim3(B_ / 128, H2_ / 128, E_), 256, 0, stream>>>(
        h, (size_t)B_ * H1_, w2t, (size_t)H2_ * H1_, b2, H2_, eo, (size_t)B_ * H2_, H1_, H1_, H1_, H2_);

    // combine
    combine_kernel<<<dim3(B_ * 16 / 256), 256, 0, stream>>>(eo, gates, out);
}